// Round 3
// 158.306 us; speedup vs baseline: 1.0770x; 1.0770x over previous
//
#include <hip/hip_runtime.h>
#include <math.h>

#define BATCH 8
#define DIMD  512
#define NTOK  1024
#define NH    8
#define CQKV  640
#define DOUT  512

typedef __attribute__((ext_vector_type(8))) short short8;
typedef __attribute__((ext_vector_type(4))) short short4v;
typedef __attribute__((ext_vector_type(4))) float f32x4;

__device__ __forceinline__ short bf16rn(float x) {
    unsigned u = __float_as_uint(x);
    u += 0x7FFF + ((u >> 16) & 1);
    return (short)(u >> 16);
}
__device__ __forceinline__ float bf16tof(short s) {
    return __uint_as_float(((unsigned)(unsigned short)s) << 16);
}
struct HL { short h, l; };
__device__ __forceinline__ HL bf16split(float x) {
    HL r;
    r.h = bf16rn(x);
    r.l = bf16rn(x - bf16tof(r.h));
    return r;
}
__device__ __forceinline__ void dma16(const short* g, short* l) {
    __builtin_amdgcn_global_load_lds(
        (const __attribute__((address_space(1))) unsigned int*)g,
        (__attribute__((address_space(3))) unsigned int*)l, 16, 0, 0);
}
// max over the 16-lane r-group: ds_swizzle xor 1,2,4,8
__device__ __forceinline__ float swzmax16(float v) {
    v = fmaxf(v, __int_as_float(__builtin_amdgcn_ds_swizzle(__float_as_int(v), 0x041F)));
    v = fmaxf(v, __int_as_float(__builtin_amdgcn_ds_swizzle(__float_as_int(v), 0x081F)));
    v = fmaxf(v, __int_as_float(__builtin_amdgcn_ds_swizzle(__float_as_int(v), 0x101F)));
    v = fmaxf(v, __int_as_float(__builtin_amdgcn_ds_swizzle(__float_as_int(v), 0x201F)));
    return v;
}
// pack (truncate) two f32 -> two bf16 in one dword
__device__ __forceinline__ unsigned packbf2(float f0, float f1) {
    return __builtin_amdgcn_perm(__float_as_uint(f1), __float_as_uint(f0), 0x07060302);
}

// Fragment-order conventions (verified end-to-end R2/R4-R13):
//  A-frag: lane=(q,r), element A[m=r][k=q*8+j] per 32-k chunk
//  B-frag: element B[ncol=r][k=q*8+j]
//  C/D   : D[m=q*4+reg][ncol=r]
// K/V frag buffers: [b][t16][ic8][lane64][j8]; Q: [b][h][nt64][kc2][lane64][j8]
// O frag buffer:    [b][nt64][ct16][lane64][j8]

// ---------------------------------------------------------------------------
// prepack_all: fused prepack_x (blocks 0-1023) + prepack_w (1024-1183) +
// prepack_wout (1184-1311).  (unchanged from R13)
// ---------------------------------------------------------------------------
__global__ __launch_bounds__(256) void prepack_all(const float* __restrict__ x,
                                                   const float* __restrict__ qp,
                                                   const float* __restrict__ kp,
                                                   const float* __restrict__ vp,
                                                   const float* __restrict__ wout,
                                                   short* __restrict__ whi,
                                                   short* __restrict__ wlo,
                                                   short* __restrict__ xhi,
                                                   short* __restrict__ xlo,
                                                   short* __restrict__ wof) {
    __shared__ float Cs[64][65];
    const int blk = blockIdx.x;
    const int t = threadIdx.x;
    if (blk < 1024) {
        const int nt = blk & 15, dt = (blk >> 4) & 7, b = blk >> 7;
        #pragma unroll
        for (int i = 0; i < 4; ++i) {
            int row = (t >> 4) + i * 16;
            float4 v = *(const float4*)(x + ((size_t)(b * DIMD + dt * 64 + row)) * NTOK
                                          + nt * 64 + (t & 15) * 4);
            Cs[row][(t & 15) * 4 + 0] = v.x;
            Cs[row][(t & 15) * 4 + 1] = v.y;
            Cs[row][(t & 15) * 4 + 2] = v.z;
            Cs[row][(t & 15) * 4 + 3] = v.w;
        }
        __syncthreads();
        for (int u = t; u < 512; u += 256) {
            int lane2 = u & 63, cidx = u >> 6;
            int q2 = lane2 >> 4, r2 = lane2 & 15;
            int kt_loc = cidx & 1, mt_loc = cidx >> 1;
            short8 h8, l8;
            #pragma unroll
            for (int j = 0; j < 8; ++j) {
                HL s = bf16split(Cs[kt_loc * 32 + q2 * 8 + j][mt_loc * 16 + r2]);
                h8[j] = s.h; l8[j] = s.l;
            }
            size_t off = (((size_t)(b * 64 + nt * 4 + mt_loc)) * 16 + dt * 2 + kt_loc) * 512
                         + lane2 * 8;
            *(short8*)&xhi[off] = h8;
            *(short8*)&xlo[off] = l8;
        }
    } else if (blk < 1184) {
        int tid = (blk - 1024) * 256 + t;
        int lane = tid & 63, kt = (tid >> 6) & 15, ct = tid >> 10;
        int q = lane >> 4, r = lane & 15;
        int c = ct * 16 + r;
        short8 h, l;
        #pragma unroll
        for (int j = 0; j < 8; ++j) {
            int d = kt * 32 + q * 8 + j;
            float v;
            if (c < 64)       v = kp[d * 64 + c];
            else if (c < 128) v = vp[d * 64 + (c - 64)];
            else              v = qp[(size_t)(c - 128) * DIMD + d];
            HL s = bf16split(v);
            h[j] = s.h; l[j] = s.l;
        }
        *(short8*)&whi[(size_t)tid * 8] = h;
        *(short8*)&wlo[(size_t)tid * 8] = l;
    } else {
        int tid = (blk - 1184) * 256 + t;
        int lane = tid & 63, kt = (tid >> 6) & 15, mt = tid >> 10;
        int q = lane >> 4, r = lane & 15;
        const float* src = wout + (size_t)(mt * 16 + r) * DOUT + kt * 32 + q * 8;
        short8 h;
        #pragma unroll
        for (int j = 0; j < 8; ++j) h[j] = bf16rn(src[j]);
        *(short8*)&wof[(size_t)tid * 8] = h;
    }
}

// ---------------------------------------------------------------------------
// qkv_gemm: split-bf16 MFMA + fused frag emission.  BM=128(n) BN=64(c):
// each wave owns 2 row-tiles so every B ds_read_b128 feeds 6 MFMAs.
// Grid 640, XCD swizzle.  LDS: 48 KB staging / Cs[128][65] epilogue alias.
// (unchanged this round)
// ---------------------------------------------------------------------------
__global__ __launch_bounds__(256) void qkv_gemm(const short* __restrict__ xhi,
                                                const short* __restrict__ xlo,
                                                const short* __restrict__ whi,
                                                const short* __restrict__ wlo,
                                                short* __restrict__ khi,
                                                short* __restrict__ klo,
                                                short* __restrict__ vf,
                                                short* __restrict__ qhi,
                                                short* __restrict__ qlo) {
    __shared__ __align__(16) char pool[49152];
    short* Ah = (short*)pool;            // 8192 shorts (16 KB)
    short* Al = Ah + 8192;               // 16 KB
    short* Bh = Al + 8192;               // 4096 shorts (8 KB)
    short* Bl = Bh + 4096;               // 8 KB
    float (*Cs)[65] = (float(*)[65])pool;   // 128*65*4 = 33280 B (alias)

    // XCD swizzle: idx = (g&7) + 8*((g>>3)*10 + cb), g = M-tile id [0,64)
    const int idx = blockIdx.x;
    const int low = idx & 7, rest = idx >> 3;
    const int cb = rest % 10, gh = rest / 10;
    const int g = gh * 8 + low;
    const int b = g >> 3, bml = g & 7;      // rows n0 = bml*128

    const int tid = threadIdx.x, w = tid >> 6, lane = tid & 63;
    const int q = lane >> 4, r = lane & 15;
    f32x4 acc[2][4];
    #pragma unroll
    for (int i = 0; i < 2; ++i)
        #pragma unroll
        for (int j = 0; j < 4; ++j) acc[i][j] = (f32x4){0.f, 0.f, 0.f, 0.f};

    for (int it = 0; it < 8; ++it) {
        __syncthreads();
        for (int u = w; u < 16; u += 4) {
            size_t ga = ((size_t)((b * 64 + bml * 8 + (u >> 1)) * 16 + it * 2 + (u & 1))) * 512 + lane * 8;
            dma16(xhi + ga, &Ah[u * 512]);
            dma16(xlo + ga, &Al[u * 512]);
            if (u < 8) {
                size_t gb = ((size_t)((cb * 4 + (u >> 1)) * 16 + it * 2 + (u & 1))) * 512 + lane * 8;
                dma16(whi + gb, &Bh[u * 512]);
                dma16(wlo + gb, &Bl[u * 512]);
            }
        }
        __syncthreads();
        #pragma unroll
        for (int kc = 0; kc < 2; ++kc) {
            short8 ah[2], al[2];
            #pragma unroll
            for (int rt = 0; rt < 2; ++rt) {
                ah[rt] = *(short8*)&Ah[((w * 2 + rt) * 2 + kc) * 512 + lane * 8];
                al[rt] = *(short8*)&Al[((w * 2 + rt) * 2 + kc) * 512 + lane * 8];
            }
            #pragma unroll
            for (int tt = 0; tt < 4; ++tt) {
                short8 bh = *(short8*)&Bh[(tt * 2 + kc) * 512 + lane * 8];
                short8 bl = *(short8*)&Bl[(tt * 2 + kc) * 512 + lane * 8];
                #pragma unroll
                for (int rt = 0; rt < 2; ++rt) {
                    acc[rt][tt] = __builtin_amdgcn_mfma_f32_16x16x32_bf16(ah[rt], bh, acc[rt][tt], 0, 0, 0);
                    acc[rt][tt] = __builtin_amdgcn_mfma_f32_16x16x32_bf16(ah[rt], bl, acc[rt][tt], 0, 0, 0);
                    acc[rt][tt] = __builtin_amdgcn_mfma_f32_16x16x32_bf16(al[rt], bh, acc[rt][tt], 0, 0, 0);
                }
            }
        }
    }

    // ---- fused epilogue: C tile (128x64) -> LDS -> frag-order bf16 global ----
    __syncthreads();
    #pragma unroll
    for (int rt = 0; rt < 2; ++rt)
        #pragma unroll
        for (int reg = 0; reg < 4; ++reg)
            #pragma unroll
            for (int tt = 0; tt < 4; ++tt)
                Cs[w * 32 + rt * 16 + q * 4 + reg][tt * 16 + r] = acc[rt][tt][reg];
    __syncthreads();

    if (cb == 0) {
        // K: 2 t-tiles; elem K[m=t*64+i*16+r2][kd=cc*32+q2*8+j], ic=i*2+cc
        for (int u = tid; u < 1024; u += 256) {
            int lane2 = u & 63, ic = (u >> 6) & 7, tl = u >> 9;
            int q2 = lane2 >> 4, r2 = lane2 & 15;
            int i = ic >> 1, cc = ic & 1;
            short8 h8, l8;
            #pragma unroll
            for (int j = 0; j < 8; ++j) {
                HL s = bf16split(Cs[tl * 64 + i * 16 + r2][cc * 32 + q2 * 8 + j]);
                h8[j] = s.h; l8[j] = s.l;
            }
            size_t off = ((size_t)(b * 16 + bml * 2 + tl) * 8 + ic) * 512 + lane2 * 8;
            *(short8*)&khi[off] = h8;
            *(short8*)&klo[off] = l8;
        }
    } else if (cb == 1) {
        // V: 2 t-tiles; elem V[m=cc*32+q2*8+j][v=tv*16+r2], ic=tv*2+cc
        for (int u = tid; u < 1024; u += 256) {
            int lane2 = u & 63, ic = (u >> 6) & 7, tl = u >> 9;
            int q2 = lane2 >> 4, r2 = lane2 & 15;
            int tv = ic >> 1, cc = ic & 1;
            short8 v8;
            #pragma unroll
            for (int j = 0; j < 8; ++j)
                v8[j] = bf16rn(Cs[tl * 64 + cc * 32 + q2 * 8 + j][tv * 16 + r2]);
            size_t off = ((size_t)(b * 16 + bml * 2 + tl) * 8 + ic) * 512 + lane2 * 8;
            *(short8*)&vf[off] = v8;
        }
    } else {
        // Q head hd: 8 nt-tiles x 2 kc = 16 chunks -> u < 1024 (R14 bug: was 2048)
        const int hd = cb - 2;
        const float qscale = 0.125f * 1.44269504f;
        for (int u = tid; u < 1024; u += 256) {
            int lane2 = u & 63, ch = u >> 6;        // ch in [0,16)
            int q2 = lane2 >> 4, r2 = lane2 & 15;
            int kc = ch & 1, ntl = ch >> 1;         // ntl in [0,8)
            short8 h8, l8;
            #pragma unroll
            for (int j = 0; j < 8; ++j) {
                HL s = bf16split(Cs[ntl * 16 + r2][kc * 32 + q2 * 8 + j] * qscale);
                h8[j] = s.h; l8[j] = s.l;
            }
            size_t off = ((((size_t)(b * 8 + hd) * 64 + bml * 8 + ntl) * 2 + kc) * 64 + lane2) * 8;
            *(short8*)&qhi[off] = h8;
            *(short8*)&qlo[off] = l8;
        }
    }
}

// ---------------------------------------------------------------------------
// attn: R16 (resubmitted R17 — prior bench was an infra failure, no verdict).
// R15 (512 thr, dbuf, 1 barrier/tile) raced: __syncthreads alone does not
// retire outstanding ds_reads (consumers are register-only MFMAs the compiler
// may sink past the barrier — trap #18), so a wave could cross the barrier
// with a Vf[cur^1] read in flight while another wave's DMA overwrote it.
// Fix: explicit sched_barrier-pinned s_waitcnt vmcnt(0) lgkmcnt(0)
// immediately before the per-tile barrier.  vmcnt(0) drains the DMA issued at
// the TOP of the previous iteration (full compute phase to land — latency
// still hidden); lgkmcnt(0) retires all LDS reads so the buffer written next
// is provably dead.  Pbuf stride 20 shorts (uint2 stores 8B-aligned on every
// row; <=2-way bank aliasing).  LDS 68 KB -> 2 blocks/CU x 8 waves =
// 16 waves/CU (4/SIMD).
// ---------------------------------------------------------------------------
__global__ __launch_bounds__(512) void attn_mfma(const short* __restrict__ qhi_g,
                                                 const short* __restrict__ qlo_g,
                                                 const short* __restrict__ khi_g,
                                                 const short* __restrict__ klo_g,
                                                 const short* __restrict__ vf_g,
                                                 short* __restrict__ ob) {
    __shared__ short Khi[2][4096], Klo[2][4096], Vf[2][4096];   // 48 KB
    __shared__ short Pbuf[8 * 64 * 20];                          // 20 KB
    const int blk = blockIdx.x;
    const int b   = blk & 7;        // XCD = blk%8 = b -> per-XCD K/V L2 locality
    const int h   = (blk >> 3) & 7;
    const int qt  = blk >> 6;
    const int tid = threadIdx.x;
    const int w    = tid >> 6;      // 8 waves
    const int lane = tid & 63;
    const int q    = lane >> 4;
    const int r    = lane & 15;
    short* Pw = Pbuf + w * (64 * 20);
    const int nt = qt * 8 + w;      // this wave's 16-row q-tile

    short8 qhi[2], qlo[2];
    #pragma unroll
    for (int c = 0; c < 2; ++c) {
        size_t off = ((((size_t)(b * 8 + h) * 64 + nt) * 2 + c) * 64 + lane) * 8;
        qhi[c] = *(const short8*)&qhi_g[off];
        qlo[c] = *(const short8*)&qlo_g[off];
    }

    short8 bones;
    #pragma unroll
    for (int j = 0; j < 8; ++j) bones[j] = (short)0x3F80;

    f32x4 oacc[4], lacc;
    float m_[4];
    #pragma unroll
    for (int tt = 0; tt < 4; ++tt) oacc[tt] = (f32x4){0.f, 0.f, 0.f, 0.f};
    lacc = (f32x4){0.f, 0.f, 0.f, 0.f};
    #pragma unroll
    for (int i = 0; i < 4; ++i) m_[i] = -1e30f;

    // prologue: DMA tile 0 into buffer 0 (each wave stages chunk ch = w)
    {
        const size_t kb = ((size_t)(b * 16 + 0) * 8) * 512;
        dma16(khi_g + kb + w * 512 + lane * 8, &Khi[0][w * 512]);
        dma16(klo_g + kb + w * 512 + lane * 8, &Klo[0][w * 512]);
        dma16(vf_g  + kb + w * 512 + lane * 8, &Vf [0][w * 512]);
    }

    for (int t = 0; t < 16; ++t) {
        const int cur = t & 1;
        // Explicit pinned drain: own DMA for buf[cur] landed (vmcnt) AND all
        // own ds_reads of buf[cur^1] retired (lgkm).  Then barrier makes it
        // workgroup-wide.  Without this, reg-only MFMA consumers can sink
        // past the barrier leaving reads in flight (the R15 race).
        __builtin_amdgcn_sched_barrier(0);
        asm volatile("s_waitcnt vmcnt(0) lgkmcnt(0)" ::: "memory");
        __builtin_amdgcn_sched_barrier(0);
        __syncthreads();
        if (t < 15) {               // issue next tile into buf[cur^1]; hides under compute
            const size_t kb = ((size_t)(b * 16 + t + 1) * 8) * 512;
            dma16(khi_g + kb + w * 512 + lane * 8, &Khi[cur ^ 1][w * 512]);
            dma16(klo_g + kb + w * 512 + lane * 8, &Klo[cur ^ 1][w * 512]);
            dma16(vf_g  + kb + w * 512 + lane * 8, &Vf [cur ^ 1][w * 512]);
        }

        // ---- QK^T: S[m=16 rows][64 keys], split-bf16 3-term ----
        f32x4 s[4];
        #pragma unroll
        for (int tt = 0; tt < 4; ++tt) s[tt] = (f32x4){0.f, 0.f, 0.f, 0.f};
        #pragma unroll
        for (int c = 0; c < 2; ++c) {
            #pragma unroll
            for (int tt = 0; tt < 4; ++tt) {
                short8 kh = *(short8*)&Khi[cur][((tt * 2 + c) * 64 + lane) * 8];
                short8 kl = *(short8*)&Klo[cur][((tt * 2 + c) * 64 + lane) * 8];
                s[tt] = __builtin_amdgcn_mfma_f32_16x16x32_bf16(qhi[c], kh, s[tt], 0, 0, 0);
                s[tt] = __builtin_amdgcn_mfma_f32_16x16x32_bf16(qhi[c], kl, s[tt], 0, 0, 0);
                s[tt] = __builtin_amdgcn_mfma_f32_16x16x32_bf16(qlo[c], kh, s[tt], 0, 0, 0);
            }
        }

        // ---- lazy online softmax (log2 space) ----
        float pmax[4];
        bool need = false;
        #pragma unroll
        for (int reg = 0; reg < 4; ++reg) {
            float pm = fmaxf(fmaxf(s[0][reg], s[1][reg]), fmaxf(s[2][reg], s[3][reg]));
            pmax[reg] = pm;
            need = need || (pm > m_[reg] + 30.f);
        }
        if (__any((int)need)) {
            #pragma unroll
            for (int reg = 0; reg < 4; ++reg) {
                float smax = swzmax16(pmax[reg]);
                float nm    = fmaxf(m_[reg], smax);
                float alpha = exp2f(m_[reg] - nm);
                m_[reg] = nm;
                lacc[reg] *= alpha;
                #pragma unroll
                for (int tt = 0; tt < 4; ++tt) oacc[tt][reg] *= alpha;
            }
        }
        #pragma unroll
        for (int reg = 0; reg < 4; ++reg)
            #pragma unroll
            for (int tt = 0; tt < 4; ++tt)
                s[tt][reg] = exp2f(s[tt][reg] - m_[reg]);

        // ---- P -> LDS (P^T layout [key][m], stride 20 shorts, 8B-aligned) ----
        #pragma unroll
        for (int tt = 0; tt < 4; ++tt) {
            uint2 pk;
            pk.x = packbf2(s[tt][0], s[tt][1]);
            pk.y = packbf2(s[tt][2], s[tt][3]);
            *(uint2*)&Pw[(r + 16 * tt) * 20 + q * 4] = pk;
        }

        // ---- PV + row-sum via MFMA ----
        #pragma unroll
        for (int c = 0; c < 2; ++c) {
            short8 pf;
            #pragma unroll
            for (int j = 0; j < 8; ++j)
                pf[j] = Pw[(c * 32 + q * 8 + j) * 20 + r];
            lacc = __builtin_amdgcn_mfma_f32_16x16x32_bf16(pf, bones, lacc, 0, 0, 0);
            #pragma unroll
            for (int tt = 0; tt < 4; ++tt) {
                short8 vfr = *(short8*)&Vf[cur][((tt * 2 + c) * 64 + lane) * 8];
                oacc[tt] = __builtin_amdgcn_mfma_f32_16x16x32_bf16(pf, vfr, oacc[tt], 0, 0, 0);
            }
        }
    }

    // ---- epilogue: O frag-order bf16 store ----
    #pragma unroll
    for (int reg = 0; reg < 4; ++reg) {
        float inv = 1.f / lacc[reg];
        #pragma unroll
        for (int tt = 0; tt < 4; ++tt) {
            int ct = h * 2 + (tt >> 1);
            int lanep = ((tt & 1) * 2 + (r >> 3)) * 16 + q * 4 + reg;
            ob[((((size_t)b * 64 + nt) * 16 + ct) * 64 + lanep) * 8 + (r & 7)] =
                bf16rn(oacc[tt][reg] * inv);
        }
    }
}

// ---------------------------------------------------------------------------
// out_gemm: plain bf16 MFMA, double-buffered staging (unchanged — short,
// uniform compute phase; has never tripped the read-retire hazard).
// ---------------------------------------------------------------------------
__global__ __launch_bounds__(256) void out_gemm(const short* __restrict__ wof,
                                                const short* __restrict__ obf,
                                                float* __restrict__ out) {
    __shared__ short Ah[2][4096];
    __shared__ short Bh[2][4096];
    const int b = blockIdx.z, bd = blockIdx.y, bn = blockIdx.x;
    const int tid = threadIdx.x, w = tid >> 6, lane = tid & 63;
    const int q = lane >> 4, r = lane & 15;
    f32x4 acc[4];
    #pragma unroll
    for (int j = 0; j < 4; ++j) acc[j] = (f32x4){0.f, 0.f, 0.f, 0.f};

    for (int u = w; u < 8; u += 4) {
        size_t ga = ((size_t)((bd * 4 + (u >> 1)) * 16 + (u & 1))) * 512 + lane * 8;
        dma16(wof + ga, &Ah[0][u * 512]);
        size_t gb = ((size_t)((b * 64 + bn * 4 + (u >> 1)) * 16 + (u & 1))) * 512 + lane * 8;
        dma16(obf + gb, &Bh[0][u * 512]);
    }

    for (int it = 0; it < 8; ++it) {
        const int cur = it & 1;
        __syncthreads();
        if (it < 7) {
            for (int u = w; u < 8; u += 4) {
                size_t ga = ((size_t)((bd * 4 + (u >> 1)) * 16 + (it + 1) * 2 + (u & 1))) * 512 + lane * 8;
                dma16(wof + ga, &Ah[cur ^ 1][u * 512]);
                size_t gb = ((size_t)((b * 64 + bn * 4 + (u >> 1)) * 16 + (it + 1) * 2 + (u & 1))) * 512 + lane * 8;
                dma16(obf + gb, &Bh[cur ^ 1][u * 512]);
            }
        }
        #pragma unroll
        for (int kc = 0; kc < 2; ++kc) {
            short8 a = *(short8*)&Ah[cur][(w * 2 + kc) * 512 + lane * 8];
            #pragma unroll
            for (int tt = 0; tt < 4; ++tt) {
                short8 bb = *(short8*)&Bh[cur][(tt * 2 + kc) * 512 + lane * 8];
                acc[tt] = __builtin_amdgcn_mfma_f32_16x16x32_bf16(a, bb, acc[tt], 0, 0, 0);
            }
        }
    }
    const int d_base = bd * 64 + w * 16;
    #pragma unroll
    for (int reg = 0; reg < 4; ++reg)
        #pragma unroll
        for (int tt = 0; tt < 4; ++tt)
            out[((size_t)b * DOUT + d_base + q * 4 + reg) * NTOK
                + bn * 64 + tt * 16 + r] = acc[tt][reg];
}

// ---------------------------------------------------------------------------
extern "C" void kernel_launch(void* const* d_in, const int* in_sizes, int n_in,
                              void* d_out, int out_size, void* d_ws, size_t ws_size,
                              hipStream_t stream) {
    const float* x  = (const float*)d_in[0];
    const float* qp = (const float*)d_in[1];
    const float* kp = (const float*)d_in[2];
    const float* vp = (const float*)d_in[3];
    const float* op = (const float*)d_in[4];
    float* out = (float*)d_out;

    // workspace: 38.5 MB (proven R12/R13)
    short* Whi = (short*)d_ws;                 // 327,680
    short* Wlo = Whi + 327680;                 // 327,680
    short* Xhi = Wlo + 327680;                 // 4,194,304
    short* Xlo = Xhi + 4194304;                // 4,194,304
    short* Qhi = Xlo + 4194304;                // 4,194,304
    short* Qlo = Qhi + 4194304;                // 4,194,304
    short* Khi = Qlo + 4194304;                // 524,288
    short* Klo = Khi + 524288;                 // 524,288
    short* Vf  = Klo + 524288;                 // 524,288
    short* Wof = Vf  + 524288;                 // 262,144
    short* Ob  = Xhi;                          // alias: X dead after qkv_gemm

    prepack_all <<<1312, 256, 0, stream>>>(x, qp, kp, vp, op,
                                           Whi, Wlo, Xhi, Xlo, Wof);
    qkv_gemm    <<<640, 256, 0, stream>>>(Xhi, Xlo, Whi, Wlo,
                                          Khi, Klo, Vf, Qhi, Qlo);
    attn_mfma   <<<512, 512, 0, stream>>>(Qhi, Qlo, Khi, Klo, Vf, Ob);
    out_gemm    <<<dim3(16, 8, BATCH), 256, 0, stream>>>(Wof, Ob, out);
}